// Round 1
// baseline (12942.776 us; speedup 1.0000x reference)
//
#include <hip/hip_runtime.h>

#define NR 4096
#define NT 720
#define TSEC 3600.0f
#define QLB 1e-4f
#define COLS_CAP 12288

// ---------------- coefficients ----------------
__global__ void coef_kernel(const float* __restrict__ raw_n,
                            const float* __restrict__ raw_q,
                            const float* __restrict__ raw_p,
                            const float* __restrict__ width,
                            const float* __restrict__ length,
                            const float* __restrict__ slope,
                            const float* __restrict__ x_storage,
                            float* __restrict__ c1, float* __restrict__ c2,
                            float* __restrict__ c3, float* __restrict__ c4) {
    int i = blockIdx.x * blockDim.x + threadIdx.x;
    if (i >= NR) return;
    float n   = 0.01f + raw_n[i] * (0.3f - 0.01f);
    float qsp = 1.5f + raw_q[i] * (3.0f - 1.5f);
    float psp = 0.5f + raw_p[i] * (2.0f - 0.5f);
    float s0  = fmaxf(slope[i], 1e-4f);
    float depth = logf(width[i] / psp) / logf(qsp);
    float v = (1.0f / n) * powf(depth, 2.0f / 3.0f) * sqrtf(s0);
    float c = fminf(fmaxf(v, 0.3f), 15.0f) * (5.0f / 3.0f);
    float k = length[i] / c;
    float x = x_storage[0];
    float denom = 2.0f * k * (1.0f - x) + TSEC;
    c1[i] = (TSEC - 2.0f * k * x) / denom;
    c2[i] = (TSEC + 2.0f * k * x) / denom;
    c3[i] = (2.0f * k * (1.0f - x) - TSEC) / denom;
    c4[i] = 2.0f * TSEC / denom;
}

// ---------------- CSR build: count ----------------
__global__ void count_kernel(const float* __restrict__ adj, int* __restrict__ cnt) {
    int row = blockIdx.x;
    int lane = threadIdx.x;
    const float* r = adj + (size_t)row * NR;
    int c = 0;
    for (int base = 0; base < NR; base += 64) {
        float v = r[base + lane];
        unsigned long long m = __ballot(v != 0.0f);
        c += __popcll(m);
    }
    if (lane == 0) cnt[row] = c;
}

// ---------------- exclusive scan (single block, 1024 thr, 4/thread) ----------------
__global__ void scan_kernel(const int* __restrict__ cnt, int* __restrict__ rowptr) {
    __shared__ int part[1024];
    int tid = threadIdx.x;
    int base = tid * 4;
    int s0 = cnt[base], s1 = cnt[base + 1], s2 = cnt[base + 2], s3 = cnt[base + 3];
    int tot = s0 + s1 + s2 + s3;
    part[tid] = tot;
    __syncthreads();
    for (int off = 1; off < 1024; off <<= 1) {
        int v = part[tid];
        int add = (tid >= off) ? part[tid - off] : 0;
        __syncthreads();
        part[tid] = v + add;
        __syncthreads();
    }
    int excl = (tid > 0) ? part[tid - 1] : 0;
    rowptr[base]     = excl;
    rowptr[base + 1] = excl + s0;
    rowptr[base + 2] = excl + s0 + s1;
    rowptr[base + 3] = excl + s0 + s1 + s2;
    if (tid == 1023) rowptr[NR] = excl + tot;
}

// ---------------- CSR build: fill (ascending cols via ballot ranks) ----------------
__global__ void fill_kernel(const float* __restrict__ adj,
                            const int* __restrict__ rowptr, int* __restrict__ cols) {
    int row = blockIdx.x;
    int lane = threadIdx.x;
    const float* r = adj + (size_t)row * NR;
    int wbase = rowptr[row];
    for (int base = 0; base < NR; base += 64) {
        float v = r[base + lane];
        unsigned long long m = __ballot(v != 0.0f);
        if (v != 0.0f) {
            int pos = __popcll(m & ((1ull << lane) - 1ull));
            cols[wbase + pos] = base + lane;
        }
        wbase += __popcll(m);
    }
}

// ---------------- DAG levels (monotone Jacobi to fixpoint) ----------------
__global__ void level_kernel(const int* __restrict__ rowptr,
                             const int* __restrict__ cols, int* __restrict__ level_g) {
    __shared__ int lev[NR];
    __shared__ int changed;
    int tid = threadIdx.x;
#pragma unroll
    for (int k = 0; k < 4; k++) lev[tid + k * 1024] = 0;
    __syncthreads();
    for (int iter = 0; iter < NR; ++iter) {
        if (tid == 0) changed = 0;
        __syncthreads();
#pragma unroll
        for (int k = 0; k < 4; k++) {
            int i = tid + k * 1024;
            int b0 = rowptr[i], b1 = rowptr[i + 1];
            int m = 0;
            for (int e = b0; e < b1; e++) {
                int l = lev[cols[e]] + 1;
                m = (l > m) ? l : m;
            }
            if (b1 > b0 && m != lev[i]) { lev[i] = m; changed = 1; }
        }
        __syncthreads();
        if (changed == 0) break;
        __syncthreads();
    }
#pragma unroll
    for (int k = 0; k < 4; k++) level_g[tid + k * 1024] = lev[tid + k * 1024];
}

// ---------------- main routing scan: single workgroup ----------------
__global__ __launch_bounds__(1024, 1) void route_kernel(
    const float* __restrict__ qp, const float* __restrict__ c1g,
    const float* __restrict__ c2g, const float* __restrict__ c3g,
    const float* __restrict__ c4g, const int* __restrict__ rowptr,
    const int* __restrict__ cols_g, const int* __restrict__ level_g,
    float* __restrict__ out) {
    __shared__ float d[NR];
    __shared__ float s[NR];
    __shared__ int cols_sh[COLS_CAP];
    __shared__ int maxlev_sh;
    int tid = threadIdx.x;
    if (tid == 0) maxlev_sh = 0;
    __syncthreads();
    int total = rowptr[NR];
    if (total > COLS_CAP) total = COLS_CAP;  // safety (practically never)
    for (int e = tid; e < total; e += 1024) cols_sh[e] = cols_g[e];

    int rp0[4], rn[4], LV[4];
    float C1[4], C2[4], C3[4], C4[4];
    int ml = 0;
#pragma unroll
    for (int k = 0; k < 4; k++) {
        int r = tid + k * 1024;
        rp0[k] = rowptr[r];
        rn[k]  = rowptr[r + 1] - rp0[k];
        C1[k] = c1g[r]; C2[k] = c2g[r]; C3[k] = c3g[r]; C4[k] = c4g[r];
        LV[k] = level_g[r];
        ml = (LV[k] > ml) ? LV[k] : ml;
    }
    atomicMax(&maxlev_sh, ml);

    float qcur[4];
#pragma unroll
    for (int k = 0; k < 4; k++) {
        int r = tid + k * 1024;
        float v = qp[r];  // q_prime row 0 = d0
        d[r] = v;
        qcur[k] = v;
    }
    if (tid == 1023) out[0] = fmaxf(qcur[3], QLB);  // d0[-1] clamped
    __syncthreads();
    int maxlev = maxlev_sh;

    float qnext[4] = {0.f, 0.f, 0.f, 0.f};
    for (int t = 1; t < NT; t++) {
        // prefetch q_prime row t (used as lateral inflow at t+1)
        if (t < NT - 1) {
#pragma unroll
            for (int k = 0; k < 4; k++)
                qnext[k] = qp[(size_t)t * NR + tid + k * 1024];
        }
        // phase A: b = c2*(A@d) + c3*d + c4*max(q_l, eps)  -> s
#pragma unroll
        for (int k = 0; k < 4; k++) {
            int r = tid + k * 1024;
            float sum = 0.0f;
            int e0 = rp0[k], e1 = rp0[k] + rn[k];
            for (int e = e0; e < e1; ++e) sum += d[cols_sh[e]];
            s[r] = C2[k] * sum + C3[k] * d[r] + C4[k] * fmaxf(qcur[k], QLB);
        }
        __syncthreads();
        // phase B: forward substitution by level: x_i = b_i + c1_i * sum(A_ij x_j)
        for (int l = 1; l <= maxlev; l++) {
#pragma unroll
            for (int k = 0; k < 4; k++) {
                if (LV[k] == l) {
                    int r = tid + k * 1024;
                    float sum = 0.0f;
                    int e0 = rp0[k], e1 = rp0[k] + rn[k];
                    for (int e = e0; e < e1; ++e) sum += s[cols_sh[e]];
                    s[r] += C1[k] * sum;
                }
            }
            __syncthreads();
        }
        // phase C: clamp, commit state, emit gage
#pragma unroll
        for (int k = 0; k < 4; k++) {
            int r = tid + k * 1024;
            float v = fmaxf(s[r], QLB);
            d[r] = v;
            if (r == NR - 1) out[t] = v;
        }
        __syncthreads();
#pragma unroll
        for (int k = 0; k < 4; k++) qcur[k] = qnext[k];
    }
}

extern "C" void kernel_launch(void* const* d_in, const int* in_sizes, int n_in,
                              void* d_out, int out_size, void* d_ws, size_t ws_size,
                              hipStream_t stream) {
    const float* q_prime  = (const float*)d_in[0];
    const float* raw_n    = (const float*)d_in[1];
    const float* raw_q    = (const float*)d_in[2];
    const float* raw_p    = (const float*)d_in[3];
    const float* width    = (const float*)d_in[4];
    const float* length   = (const float*)d_in[5];
    const float* slope    = (const float*)d_in[6];
    const float* adj      = (const float*)d_in[7];
    const float* x_stor   = (const float*)d_in[8];
    float* out = (float*)d_out;

    // workspace layout
    float* ws_f = (float*)d_ws;
    float* c1 = ws_f;
    float* c2 = ws_f + NR;
    float* c3 = ws_f + 2 * NR;
    float* c4 = ws_f + 3 * NR;
    int* ws_i = (int*)(ws_f + 4 * NR);
    int* cnt    = ws_i;                 // NR
    int* rowptr = ws_i + NR;            // NR+1 (padded to NR+8)
    int* cols   = ws_i + 2 * NR + 8;    // COLS_CAP*2 safety cap region
    int* level  = cols + 2 * COLS_CAP;  // NR

    coef_kernel<<<(NR + 255) / 256, 256, 0, stream>>>(raw_n, raw_q, raw_p, width,
                                                      length, slope, x_stor,
                                                      c1, c2, c3, c4);
    count_kernel<<<NR, 64, 0, stream>>>(adj, cnt);
    scan_kernel<<<1, 1024, 0, stream>>>(cnt, rowptr);
    fill_kernel<<<NR, 64, 0, stream>>>(adj, rowptr, cols);
    level_kernel<<<1, 1024, 0, stream>>>(rowptr, cols, level);
    route_kernel<<<1, 1024, 0, stream>>>(q_prime, c1, c2, c3, c4, rowptr, cols,
                                         level, out);
}